// Round 1
// baseline (240.538 us; speedup 1.0000x reference)
//
#include <hip/hip_runtime.h>
#include <hip/hip_bf16.h>

using bf16x8 = __attribute__((ext_vector_type(8))) short;
using f32x4  = __attribute__((ext_vector_type(4))) float;

constexpr int cV  = 50257;
constexpr int cD  = 128;
constexpr int cN  = 512;
constexpr int cH  = 8;
constexpr int cDH = 16;
constexpr int cS  = 256;

#define PHI_F    1.6180339887498949f
#define INV2PI_F 0.15915494309189535f
#define SQRT2_F  1.4142135623730951f

__device__ __forceinline__ float fract1(float x) { return x - floorf(x); }

#if __has_builtin(__builtin_amdgcn_sinf)
__device__ __forceinline__ float sin_rev(float r) { return __builtin_amdgcn_sinf(r); }   // sin(2*pi*r)
__device__ __forceinline__ float cos_rev(float r) { return __builtin_amdgcn_cosf(r); }   // cos(2*pi*r)
#else
__device__ __forceinline__ float sin_rev(float r) { return __sinf(r * 6.2831853071795865f); }
__device__ __forceinline__ float cos_rev(float r) { return __cosf(r * 6.2831853071795865f); }
#endif

__device__ __forceinline__ unsigned short f2bf(float f) {
  unsigned u = __float_as_uint(f);
  unsigned r = (u + 0x7FFFu + ((u >> 16) & 1u)) >> 16;
  return (unsigned short)r;
}

// ---------------- P0: scan-constant prep -----------------------------------
// mc[s*256 + (b*128+d)] = {sqrt2/(1+|w_e|)/2pi , (b_e + s*phi)/2pi + 1/8}
__global__ void k_prep_mc(const int* __restrict__ tokens, const float* __restrict__ emb,
                          float2* __restrict__ mc) {
  int idx = blockIdx.x * 256 + threadIdx.x;        // 65536 = S * (B*D)
  int t = idx & 255, s = idx >> 8;
  int b = t >> 7, d = t & 127;
  int tok = tokens[b * cS + s];
  float w  = emb[tok * (2 * cD) + d];
  float be = emb[tok * (2 * cD) + cD + d];
  float m2 = SQRT2_F * INV2PI_F / (1.f + fabsf(w));
  float c  = fmaf((float)s, PHI_F, be) * INV2PI_F + 0.125f;
  mc[idx] = make_float2(m2, c);
}

// ---------------- P1: transpose proj to [l][n][d] ---------------------------
__global__ void k_transpose_proj(const float* __restrict__ pr, const float* __restrict__ pi,
                                 float* __restrict__ pTR, float* __restrict__ pTI) {
  int idx = blockIdx.x * 256 + threadIdx.x;        // L*N*D = 131072 (write-coalesced)
  int l = idx >> 16, rem = idx & 65535;
  int n = rem >> 7, d = rem & 127;
  int src = (l * cD + d) * cN + n;
  pTR[idx] = pr[src];
  pTI[idx] = pi[src];
}

// ---------------- sequential scan -------------------------------------------
__global__ void k_scan(const float2* __restrict__ mc, float* __restrict__ states) {
  int t = threadIdx.x;                              // 256 = B*D
  int b = t >> 7, d = t & 127;
  float2 buf[8];
#pragma unroll
  for (int i = 0; i < 8; ++i) buf[i] = mc[i * 256 + t];
  float sv = 0.f;
  float* out = states + (b * cS) * cD + d;
#pragma unroll 8
  for (int s = 0; s < cS; ++s) {
    float2 v = buf[s & 7];
    if (s + 8 < cS) buf[s & 7] = mc[(s + 8) * 256 + t];
    float r = fmaf(sv, v.x, v.y);
    sv = sin_rev(fract1(r));                        // state = sqrt2*sin(theta+pi/4); sqrt2 folded into m
    out[s * cD] = sv * SQRT2_F;
  }
}

// ---------------- Q/K build (per layer) -------------------------------------
__global__ void k_qk(const float* __restrict__ x, const float* __restrict__ states,
                     const float* __restrict__ wq, const float* __restrict__ bq,
                     const float* __restrict__ wk, const float* __restrict__ bk,
                     float* __restrict__ Q, float* __restrict__ Kt) {
  int idx = blockIdx.x * 256 + threadIdx.x;        // 65536 = B*S*H*DH
  int dd = idx & 15, h = (idx >> 4) & 7, s = (idx >> 7) & 255, b = idx >> 15;
  int hd = h * cDH + dd;
  int rowi = (b * cS + s) * cD + hd;
  float xv = x[rowi];
  float sv = states[rowi];
  float rq = 1.f / (1.f + fabsf(wq[hd]));
  float rk = 1.f / (1.f + fabsf(wk[hd]));
  float thq = fmaf(xv, rq, fmaf((float)s, PHI_F, bq[hd])) * INV2PI_F;
  float thk = fmaf(sv, rk, bk[hd]) * INV2PI_F;
  float fq = fract1(thq), fk = fract1(thk);
  int base = ((b * cS + s) * cH + h) * (2 * cDH) + dd;
  Q[base]        = cos_rev(fq);
  Q[base + cDH]  = sin_rev(fq);
  Kt[base]       = cos_rev(fk);
  Kt[base + cDH] = sin_rev(fk);
}

// ---------------- fused attention (per layer): one block per (b,q) ----------
__global__ __launch_bounds__(256) void k_attn(const float* __restrict__ Q, const float* __restrict__ Kt,
                                              const float* __restrict__ states, float* __restrict__ ctx) {
  int bq = blockIdx.x;                              // 512 = B*S
  int b = bq >> 8, q = bq & 255;
  int t = threadIdx.x;
  __shared__ __align__(16) float qrow[256];
  __shared__ float Psum[256];
  __shared__ float red[8];
  __shared__ float cred[256];
  qrow[t] = Q[bq * 256 + t];
  Psum[t] = 0.f;
  __syncthreads();
  bool act = (t <= q);
  float sc[8];
  {
    const float4* Kr = (const float4*)(Kt + (b * cS + t) * 256);
#pragma unroll
    for (int h = 0; h < 8; ++h) {
      float sacc = 0.f;
      if (act) {
#pragma unroll
        for (int j = 0; j < 8; ++j) {
          float4 kv = Kr[h * 8 + j];
          const float* qp = &qrow[h * 32 + j * 4];
          sacc += qp[0] * kv.x + qp[1] * kv.y + qp[2] * kv.z + qp[3] * kv.w;
        }
      }
      sc[h] = act ? sacc * 0.17677669529663689f : -3.0e38f;   // 1/sqrt(2*DH)
    }
  }
  int wid = t >> 6;
  for (int h = 0; h < 8; ++h) {
    float v = sc[h];
#pragma unroll
    for (int off = 32; off; off >>= 1) v = fmaxf(v, __shfl_xor(v, off, 64));
    if ((t & 63) == 0) red[wid] = v;
    __syncthreads();
    float m = fmaxf(fmaxf(red[0], red[1]), fmaxf(red[2], red[3]));
    float p = act ? __expf(sc[h] - m) : 0.f;
    float ps = p;
#pragma unroll
    for (int off = 32; off; off >>= 1) ps += __shfl_xor(ps, off, 64);
    if ((t & 63) == 0) red[4 + wid] = ps;
    __syncthreads();
    float tot = red[4] + red[5] + red[6] + red[7];
    Psum[t] += p / tot;
  }
  __syncthreads();
  int d = t & 127, half = t >> 7;
  float acc = 0.f;
  int k0 = half * 128;
  int kend = min(k0 + 128, q + 1);
  for (int kk = k0; kk < kend; ++kk)
    acc = fmaf(Psum[kk], states[(b * cS + kk) * cD + d], acc);
  cred[t] = acc;
  __syncthreads();
  if (half == 0) ctx[bq * cD + d] = cred[t] + cred[t + 128];
}

// ---------------- th_f cos/sin sums (per layer) ------------------------------
// grid 256 = 16 n-slabs x 16 token-groups; 512 threads = 32 n x 16 tok-slots
__global__ __launch_bounds__(512) void k_fsum(const float* __restrict__ x, const float* __restrict__ Wf,
                                              const float* __restrict__ Bf,
                                              float* __restrict__ U, float* __restrict__ Vv) {
  int ns = blockIdx.x & 15, tg = blockIdx.x >> 4;
  constexpr int P = 130;                            // pad: bank-safe + float2-aligned
  __shared__ __align__(16) float finv[32 * P];
  __shared__ __align__(16) float fb[32 * P];
  __shared__ __align__(16) float xl[32 * 128];
  int t = threadIdx.x;
#pragma unroll
  for (int i = 0; i < 8; ++i) {
    int idx = t + i * 512;
    int rl = idx >> 7, d = idx & 127;
    int g = (ns * 32 + rl) * cD + d;
    finv[rl * P + d] = INV2PI_F / (1.f + fabsf(Wf[g]));
    fb[rl * P + d]   = Bf[g] * INV2PI_F;
    xl[idx] = x[(tg * 32 + rl) * cD + d];
  }
  __syncthreads();
  int nl = t & 31, tli = t >> 5;                    // 16 token slots
#pragma unroll
  for (int p = 0; p < 2; ++p) {
    int tl = p * 16 + tli;
    int T = tg * 32 + tl;
    float srev = (float)(T & 255) * INV2PI_F;       // + t (plain s) term, in revolutions
    float uc = 0.f, us = 0.f;
    const float* fi  = finv + nl * P;
    const float* fbp = fb + nl * P;
    const float* xr  = xl + tl * 128;
#pragma unroll 4
    for (int d = 0; d < cD; d += 2) {
      float2 fiv = *(const float2*)(fi + d);
      float2 fbv = *(const float2*)(fbp + d);
      float2 xv  = *(const float2*)(xr + d);
      float f0 = fract1(fmaf(xv.x, fiv.x, fbv.x) + srev);
      float f1 = fract1(fmaf(xv.y, fiv.y, fbv.y) + srev);
      uc += cos_rev(f0);
      us += sin_rev(f0);
      uc += cos_rev(f1);
      us += sin_rev(f1);
    }
    U[T * cN + ns * 32 + nl]  = uc;
    Vv[T * cN + ns * 32 + nl] = us;
  }
}

// ---------------- res projection + attn-out + combine (per layer) ------------
// grid 256 blocks x 128 threads; block = 2 tokens; lanes: d4=t&31, g=t>>5 -> tok=g&1, nh=g>>1
__global__ __launch_bounds__(128) void k_res(const float* __restrict__ U, const float* __restrict__ Vv,
                                             const float* __restrict__ pTR, const float* __restrict__ pTI,
                                             const float* __restrict__ ctx, const float* __restrict__ x,
                                             const float* __restrict__ w_out, const float* __restrict__ b_out,
                                             const float* __restrict__ out_scale,
                                             const float* __restrict__ attn_scale, const float* __restrict__ res_scale,
                                             int l, float* __restrict__ xout) {
  int blk = blockIdx.x;
  int t = threadIdx.x;
  __shared__ __align__(16) float uv[2][512][2];
  __shared__ __align__(16) float4 part[64];
#pragma unroll
  for (int i = 0; i < 8; ++i) {
    int idx = t + i * 128;                          // 1024 = 2 tok * 512 n
    int tok = idx >> 9, n = idx & 511;
    uv[tok][n][0] = U[(blk * 2 + tok) * cN + n];
    uv[tok][n][1] = Vv[(blk * 2 + tok) * cN + n];
  }
  __syncthreads();
  int d4 = t & 31, g = t >> 5, tok = g & 1, nh = g >> 1;
  int T = blk * 2 + tok, s = T & 255;
  float a0 = 0.f, a1 = 0.f, a2 = 0.f, a3 = 0.f;
  const float* prB = pTR + (size_t)(l * cN) * cD + d4 * 4;
  const float* piB = pTI + (size_t)(l * cN) * cD + d4 * 4;
  int nEnd = nh * 256 + 256;
  for (int n = nh * 256; n < nEnd; ++n) {
    float4 pr = *(const float4*)(prB + n * cD);
    float4 pi = *(const float4*)(piB + n * cD);
    float2 w = *(const float2*)&uv[tok][n][0];
    a0 = fmaf(w.x, pr.x, fmaf(w.y, pi.x, a0));
    a1 = fmaf(w.x, pr.y, fmaf(w.y, pi.y, a1));
    a2 = fmaf(w.x, pr.z, fmaf(w.y, pi.z, a2));
    a3 = fmaf(w.x, pr.w, fmaf(w.y, pi.w, a3));
  }
  if (nh == 1) part[t - 64] = make_float4(a0, a1, a2, a3);
  __syncthreads();
  if (nh == 0) {
    float4 p2 = part[t];
    float rr[4] = { a0 + p2.x, a1 + p2.y, a2 + p2.z, a3 + p2.w };
    int di = d4 * 4;
    float4 cx  = *(const float4*)(ctx + T * cD + di);
    float4 wo  = *(const float4*)(w_out + l * cD + di);
    float4 bo  = *(const float4*)(b_out + l * cD + di);
    float4 osc = *(const float4*)(out_scale + l * cD + di);
    float4 xv  = *(const float4*)(x + T * cD + di);
    float as = attn_scale[l], rs = res_scale[l];
    float sphi = (float)s * PHI_F;
    float cxa[4] = { cx.x, cx.y, cx.z, cx.w };
    float woa[4] = { wo.x, wo.y, wo.z, wo.w };
    float boa[4] = { bo.x, bo.y, bo.z, bo.w };
    float osa[4] = { osc.x, osc.y, osc.z, osc.w };
    float xva[4] = { xv.x, xv.y, xv.z, xv.w };
    float oa[4];
#pragma unroll
    for (int c = 0; c < 4; ++c) {
      float th = fmaf(cxa[c], 1.f / (1.f + fabsf(woa[c])), boa[c]) + sphi;
      float f = fract1(th * INV2PI_F);
      float ao = osa[c] * (cos_rev(f) + sin_rev(f));
      float r = rr[c];
      float sil = r / (1.f + __expf(-r));
      oa[c] = fmaf(as, ao, fmaf(rs, sil, xva[c]));
    }
    *(float4*)(xout + T * cD + di) = make_float4(oa[0], oa[1], oa[2], oa[3]);
  }
}

// ---------------- final logits GEMM: (512x128)*(128xV), bf16 MFMA ------------
__global__ __launch_bounds__(256) void k_gemm(const float* __restrict__ X, const float* __restrict__ W,
                                              float* __restrict__ out) {
  __shared__ __align__(16) unsigned short Al[128 * 128];
  __shared__ __align__(16) unsigned short Bl[128 * 128];
  int t = threadIdx.x;
  int m0 = (blockIdx.x & 3) * 128;
  int v0 = (blockIdx.x >> 2) * 128;
#pragma unroll
  for (int i = 0; i < 16; ++i) {
    int idx = t + i * 256;
    int row = idx >> 5, c4 = idx & 31;
    float4 xv = *(const float4*)(X + (m0 + row) * cD + c4 * 4);
    ushort4 b4 = { f2bf(xv.x), f2bf(xv.y), f2bf(xv.z), f2bf(xv.w) };
    int byte = (row * 256 + c4 * 8) ^ ((row & 7) << 4);
    *(ushort4*)((char*)Al + byte) = b4;
  }
#pragma unroll
  for (int i = 0; i < 16; ++i) {
    int idx = t + i * 256;
    int row = idx >> 5, c4 = idx & 31;
    int v = v0 + row;
    float4 wv;
    if (v < cV) wv = *(const float4*)(W + (size_t)v * cD + c4 * 4);
    else { wv.x = 0.f; wv.y = 0.f; wv.z = 0.f; wv.w = 0.f; }
    ushort4 b4 = { f2bf(wv.x), f2bf(wv.y), f2bf(wv.z), f2bf(wv.w) };
    int byte = (row * 256 + c4 * 8) ^ ((row & 7) << 4);
    *(ushort4*)((char*)Bl + byte) = b4;
  }
  __syncthreads();
  int wid = t >> 6, lane = t & 63;
  int wm = (wid >> 1) * 64, wv_ = (wid & 1) * 64;
  int lr = lane & 15, lk = lane >> 4;
  f32x4 acc[4][4];
#pragma unroll
  for (int fm = 0; fm < 4; ++fm)
#pragma unroll
    for (int fv = 0; fv < 4; ++fv) acc[fm][fv] = (f32x4){0.f, 0.f, 0.f, 0.f};
#pragma unroll
  for (int ks = 0; ks < 4; ++ks) {
    bf16x8 af[4], bfv[4];
#pragma unroll
    for (int fm = 0; fm < 4; ++fm) {
      int row = wm + fm * 16 + lr;
      int byte = (row * 256 + (ks * 32 + lk * 8) * 2) ^ ((row & 7) << 4);
      af[fm] = *(const bf16x8*)((const char*)Al + byte);
    }
#pragma unroll
    for (int fv = 0; fv < 4; ++fv) {
      int row = wv_ + fv * 16 + lr;
      int byte = (row * 256 + (ks * 32 + lk * 8) * 2) ^ ((row & 7) << 4);
      bfv[fv] = *(const bf16x8*)((const char*)Bl + byte);
    }
#pragma unroll
    for (int fm = 0; fm < 4; ++fm)
#pragma unroll
      for (int fv = 0; fv < 4; ++fv)
        acc[fm][fv] = __builtin_amdgcn_mfma_f32_16x16x32_bf16(af[fm], bfv[fv], acc[fm][fv], 0, 0, 0);
  }
#pragma unroll
  for (int fm = 0; fm < 4; ++fm) {
    int rbase = m0 + wm + fm * 16 + lk * 4;
#pragma unroll
    for (int fv = 0; fv < 4; ++fv) {
      int col = v0 + wv_ + fv * 16 + lr;
      if (col < cV) {
#pragma unroll
        for (int r = 0; r < 4; ++r)
          out[(size_t)(rbase + r) * cV + col] = acc[fm][fv][r];
      }
    }
  }
}

extern "C" void kernel_launch(void* const* d_in, const int* in_sizes, int n_in,
                              void* d_out, int out_size, void* d_ws, size_t ws_size,
                              hipStream_t stream) {
  const int*   tokens    = (const int*)d_in[0];
  const float* emb       = (const float*)d_in[1];
  const float* wq        = (const float*)d_in[2];
  const float* bq        = (const float*)d_in[3];
  const float* wk        = (const float*)d_in[4];
  const float* bk        = (const float*)d_in[5];
  const float* w_out     = (const float*)d_in[6];
  const float* b_out     = (const float*)d_in[7];
  const float* out_scale = (const float*)d_in[8];
  const float* Wf        = (const float*)d_in[9];
  const float* Bf        = (const float*)d_in[10];
  const float* pr        = (const float*)d_in[11];
  const float* pi        = (const float*)d_in[12];
  const float* attn_s    = (const float*)d_in[13];
  const float* res_s     = (const float*)d_in[14];
  const float* out_proj  = (const float*)d_in[15];
  float* out = (float*)d_out;
  float* ws  = (float*)d_ws;

  float*  states = ws;                 // 65536
  float*  x1     = ws + 65536;         // 65536
  float*  x2     = ws + 131072;        // 65536
  float*  ctx    = ws + 196608;        // 65536
  float2* mc     = (float2*)(ws + 262144); // 131072 floats
  float*  Q      = ws + 393216;        // 131072
  float*  Kt     = ws + 524288;        // 131072
  float*  U      = ws + 655360;        // 262144
  float*  Vv     = ws + 917504;        // 262144
  float*  pTR    = ws + 1179648;       // 131072
  float*  pTI    = ws + 1310720;       // 131072 (total 5.77 MB)

  k_prep_mc<<<256, 256, 0, stream>>>(tokens, emb, mc);
  k_transpose_proj<<<512, 256, 0, stream>>>(pr, pi, pTR, pTI);
  k_scan<<<1, 256, 0, stream>>>(mc, states);

  const float* xin = states;
  float* xouts[2] = { x1, x2 };
  for (int l = 0; l < 2; ++l) {
    k_qk<<<256, 256, 0, stream>>>(xin, states, wq + l * 128, bq + l * 128,
                                  wk + l * 128, bk + l * 128, Q, Kt);
    k_attn<<<512, 256, 0, stream>>>(Q, Kt, states, ctx);
    k_fsum<<<256, 512, 0, stream>>>(xin, Wf + l * 65536, Bf + l * 65536, U, Vv);
    k_res<<<256, 128, 0, stream>>>(U, Vv, pTR, pTI, ctx, xin, w_out, b_out, out_scale,
                                   attn_s, res_s, l, xouts[l]);
    xin = xouts[l];
  }
  k_gemm<<<4 * ((cV + 127) / 128), 256, 0, stream>>>(x2, out_proj, out);
}

// Round 2
// 232.400 us; speedup vs baseline: 1.0350x; 1.0350x over previous
//
#include <hip/hip_runtime.h>
#include <hip/hip_bf16.h>

using bf16x8 = __attribute__((ext_vector_type(8))) short;
using f32x4  = __attribute__((ext_vector_type(4))) float;

constexpr int cV  = 50257;
constexpr int cD  = 128;
constexpr int cN  = 512;
constexpr int cH  = 8;
constexpr int cDH = 16;
constexpr int cS  = 256;

#define PHI_F    1.6180339887498949f
#define INV2PI_F 0.15915494309189535f
#define SQRT2_F  1.4142135623730951f

__device__ __forceinline__ float fract1(float x) { return x - floorf(x); }

#if __has_builtin(__builtin_amdgcn_sinf)
__device__ __forceinline__ float sin_rev(float r) { return __builtin_amdgcn_sinf(r); }   // sin(2*pi*r)
__device__ __forceinline__ float cos_rev(float r) { return __builtin_amdgcn_cosf(r); }   // cos(2*pi*r)
#else
__device__ __forceinline__ float sin_rev(float r) { return __sinf(r * 6.2831853071795865f); }
__device__ __forceinline__ float cos_rev(float r) { return __cosf(r * 6.2831853071795865f); }
#endif

__device__ __forceinline__ unsigned short f2bf(float f) {
  unsigned u = __float_as_uint(f);
  unsigned r = (u + 0x7FFFu + ((u >> 16) & 1u)) >> 16;
  return (unsigned short)r;
}

// ---------------- P0: scan-constant prep -----------------------------------
__global__ void k_prep_mc(const int* __restrict__ tokens, const float* __restrict__ emb,
                          float2* __restrict__ mc) {
  int idx = blockIdx.x * 256 + threadIdx.x;        // 65536 = S * (B*D)
  int t = idx & 255, s = idx >> 8;
  int b = t >> 7, d = t & 127;
  int tok = tokens[b * cS + s];
  float w  = emb[tok * (2 * cD) + d];
  float be = emb[tok * (2 * cD) + cD + d];
  float m2 = SQRT2_F * INV2PI_F / (1.f + fabsf(w));
  float c  = fmaf((float)s, PHI_F, be) * INV2PI_F + 0.125f;
  mc[idx] = make_float2(m2, c);
}

// ---------------- P1: transpose proj to [l][n][d] ---------------------------
__global__ void k_transpose_proj(const float* __restrict__ pr, const float* __restrict__ pi,
                                 float* __restrict__ pTR, float* __restrict__ pTI) {
  int idx = blockIdx.x * 256 + threadIdx.x;        // L*N*D = 131072 (write-coalesced)
  int l = idx >> 16, rem = idx & 65535;
  int n = rem >> 7, d = rem & 127;
  int src = (l * cD + d) * cN + n;
  pTR[idx] = pr[src];
  pTI[idx] = pi[src];
}

// ---------------- sequential scan -------------------------------------------
__global__ void k_scan(const float2* __restrict__ mc, float* __restrict__ states) {
  int t = threadIdx.x;                              // 256 = B*D
  int b = t >> 7, d = t & 127;
  float2 buf[8];
#pragma unroll
  for (int i = 0; i < 8; ++i) buf[i] = mc[i * 256 + t];
  float sv = 0.f;
  float* out = states + (b * cS) * cD + d;
#pragma unroll 8
  for (int s = 0; s < cS; ++s) {
    float2 v = buf[s & 7];
    if (s + 8 < cS) buf[s & 7] = mc[(s + 8) * 256 + t];
    float r = fmaf(sv, v.x, v.y);
    sv = sin_rev(fract1(r));                        // state = sqrt2*sin(theta+pi/4); sqrt2 folded into m
    out[s * cD] = sv * SQRT2_F;
  }
}

// ---------------- Q/K build (per layer) -------------------------------------
__global__ void k_qk(const float* __restrict__ x, const float* __restrict__ states,
                     const float* __restrict__ wq, const float* __restrict__ bq,
                     const float* __restrict__ wk, const float* __restrict__ bk,
                     float* __restrict__ Q, float* __restrict__ Kt) {
  int idx = blockIdx.x * 256 + threadIdx.x;        // 65536 = B*S*H*DH
  int dd = idx & 15, h = (idx >> 4) & 7, s = (idx >> 7) & 255, b = idx >> 15;
  int hd = h * cDH + dd;
  int rowi = (b * cS + s) * cD + hd;
  float xv = x[rowi];
  float sv = states[rowi];
  float rq = 1.f / (1.f + fabsf(wq[hd]));
  float rk = 1.f / (1.f + fabsf(wk[hd]));
  float thq = fmaf(xv, rq, fmaf((float)s, PHI_F, bq[hd])) * INV2PI_F;
  float thk = fmaf(sv, rk, bk[hd]) * INV2PI_F;
  float fq = fract1(thq), fk = fract1(thk);
  int base = ((b * cS + s) * cH + h) * (2 * cDH) + dd;
  Q[base]        = cos_rev(fq);
  Q[base + cDH]  = sin_rev(fq);
  Kt[base]       = cos_rev(fk);
  Kt[base + cDH] = sin_rev(fk);
}

// ---------------- fused attention (per layer): one block per (b,q) ----------
__global__ __launch_bounds__(256) void k_attn(const float* __restrict__ Q, const float* __restrict__ Kt,
                                              const float* __restrict__ states, float* __restrict__ ctx) {
  int bq = blockIdx.x;                              // 512 = B*S
  int b = bq >> 8, q = bq & 255;
  int t = threadIdx.x;
  __shared__ __align__(16) float qrow[256];
  __shared__ float Psum[256];
  __shared__ float red[8];
  __shared__ float cred[256];
  qrow[t] = Q[bq * 256 + t];
  Psum[t] = 0.f;
  __syncthreads();
  bool act = (t <= q);
  float sc[8];
  {
    const float4* Kr = (const float4*)(Kt + (b * cS + t) * 256);
#pragma unroll
    for (int h = 0; h < 8; ++h) {
      float sacc = 0.f;
      if (act) {
#pragma unroll
        for (int j = 0; j < 8; ++j) {
          float4 kv = Kr[h * 8 + j];
          const float* qp = &qrow[h * 32 + j * 4];
          sacc += qp[0] * kv.x + qp[1] * kv.y + qp[2] * kv.z + qp[3] * kv.w;
        }
      }
      sc[h] = act ? sacc * 0.17677669529663689f : -3.0e38f;   // 1/sqrt(2*DH)
    }
  }
  int wid = t >> 6;
  for (int h = 0; h < 8; ++h) {
    float v = sc[h];
#pragma unroll
    for (int off = 32; off; off >>= 1) v = fmaxf(v, __shfl_xor(v, off, 64));
    if ((t & 63) == 0) red[wid] = v;
    __syncthreads();
    float m = fmaxf(fmaxf(red[0], red[1]), fmaxf(red[2], red[3]));
    float p = act ? __expf(sc[h] - m) : 0.f;
    float ps = p;
#pragma unroll
    for (int off = 32; off; off >>= 1) ps += __shfl_xor(ps, off, 64);
    if ((t & 63) == 0) red[4 + wid] = ps;
    __syncthreads();
    float tot = red[4] + red[5] + red[6] + red[7];
    Psum[t] += p / tot;
  }
  __syncthreads();
  int d = t & 127, half = t >> 7;
  float acc = 0.f;
  int k0 = half * 128;
  int kend = min(k0 + 128, q + 1);
  for (int kk = k0; kk < kend; ++kk)
    acc = fmaf(Psum[kk], states[(b * cS + kk) * cD + d], acc);
  cred[t] = acc;
  __syncthreads();
  if (half == 0) ctx[bq * cD + d] = cred[t] + cred[t + 128];
}

// ---------------- th_f cos/sin sums (per layer) ------------------------------
__global__ __launch_bounds__(512) void k_fsum(const float* __restrict__ x, const float* __restrict__ Wf,
                                              const float* __restrict__ Bf,
                                              float* __restrict__ U, float* __restrict__ Vv) {
  int ns = blockIdx.x & 15, tg = blockIdx.x >> 4;
  constexpr int P = 130;                            // pad: bank-safe + float2-aligned
  __shared__ __align__(16) float finv[32 * P];
  __shared__ __align__(16) float fb[32 * P];
  __shared__ __align__(16) float xl[32 * 128];
  int t = threadIdx.x;
#pragma unroll
  for (int i = 0; i < 8; ++i) {
    int idx = t + i * 512;
    int rl = idx >> 7, d = idx & 127;
    int g = (ns * 32 + rl) * cD + d;
    finv[rl * P + d] = INV2PI_F / (1.f + fabsf(Wf[g]));
    fb[rl * P + d]   = Bf[g] * INV2PI_F;
    xl[idx] = x[(tg * 32 + rl) * cD + d];
  }
  __syncthreads();
  int nl = t & 31, tli = t >> 5;                    // 16 token slots
#pragma unroll
  for (int p = 0; p < 2; ++p) {
    int tl = p * 16 + tli;
    int T = tg * 32 + tl;
    float srev = (float)(T & 255) * INV2PI_F;       // + t (plain s) term, in revolutions
    float uc = 0.f, us = 0.f;
    const float* fi  = finv + nl * P;
    const float* fbp = fb + nl * P;
    const float* xr  = xl + tl * 128;
#pragma unroll 4
    for (int d = 0; d < cD; d += 2) {
      float2 fiv = *(const float2*)(fi + d);
      float2 fbv = *(const float2*)(fbp + d);
      float2 xv  = *(const float2*)(xr + d);
      float f0 = fract1(fmaf(xv.x, fiv.x, fbv.x) + srev);
      float f1 = fract1(fmaf(xv.y, fiv.y, fbv.y) + srev);
      uc += cos_rev(f0);
      us += sin_rev(f0);
      uc += cos_rev(f1);
      us += sin_rev(f1);
    }
    U[T * cN + ns * 32 + nl]  = uc;
    Vv[T * cN + ns * 32 + nl] = us;
  }
}

// ---------------- res projection + attn-out + combine (per layer) ------------
__global__ __launch_bounds__(128) void k_res(const float* __restrict__ U, const float* __restrict__ Vv,
                                             const float* __restrict__ pTR, const float* __restrict__ pTI,
                                             const float* __restrict__ ctx, const float* __restrict__ x,
                                             const float* __restrict__ w_out, const float* __restrict__ b_out,
                                             const float* __restrict__ out_scale,
                                             const float* __restrict__ attn_scale, const float* __restrict__ res_scale,
                                             int l, float* __restrict__ xout) {
  int blk = blockIdx.x;
  int t = threadIdx.x;
  __shared__ __align__(16) float uv[2][512][2];
  __shared__ __align__(16) float4 part[64];
#pragma unroll
  for (int i = 0; i < 8; ++i) {
    int idx = t + i * 128;                          // 1024 = 2 tok * 512 n
    int tok = idx >> 9, n = idx & 511;
    uv[tok][n][0] = U[(blk * 2 + tok) * cN + n];
    uv[tok][n][1] = Vv[(blk * 2 + tok) * cN + n];
  }
  __syncthreads();
  int d4 = t & 31, g = t >> 5, tok = g & 1, nh = g >> 1;
  int T = blk * 2 + tok, s = T & 255;
  float a0 = 0.f, a1 = 0.f, a2 = 0.f, a3 = 0.f;
  const float* prB = pTR + (size_t)(l * cN) * cD + d4 * 4;
  const float* piB = pTI + (size_t)(l * cN) * cD + d4 * 4;
  int nEnd = nh * 256 + 256;
  for (int n = nh * 256; n < nEnd; ++n) {
    float4 pr = *(const float4*)(prB + n * cD);
    float4 pi = *(const float4*)(piB + n * cD);
    float2 w = *(const float2*)&uv[tok][n][0];
    a0 = fmaf(w.x, pr.x, fmaf(w.y, pi.x, a0));
    a1 = fmaf(w.x, pr.y, fmaf(w.y, pi.y, a1));
    a2 = fmaf(w.x, pr.z, fmaf(w.y, pi.z, a2));
    a3 = fmaf(w.x, pr.w, fmaf(w.y, pi.w, a3));
  }
  if (nh == 1) part[t - 64] = make_float4(a0, a1, a2, a3);
  __syncthreads();
  if (nh == 0) {
    float4 p2 = part[t];
    float rr[4] = { a0 + p2.x, a1 + p2.y, a2 + p2.z, a3 + p2.w };
    int di = d4 * 4;
    float4 cx  = *(const float4*)(ctx + T * cD + di);
    float4 wo  = *(const float4*)(w_out + l * cD + di);
    float4 bo  = *(const float4*)(b_out + l * cD + di);
    float4 osc = *(const float4*)(out_scale + l * cD + di);
    float4 xv  = *(const float4*)(x + T * cD + di);
    float as = attn_scale[l], rs = res_scale[l];
    float sphi = (float)s * PHI_F;
    float cxa[4] = { cx.x, cx.y, cx.z, cx.w };
    float woa[4] = { wo.x, wo.y, wo.z, wo.w };
    float boa[4] = { bo.x, bo.y, bo.z, bo.w };
    float osa[4] = { osc.x, osc.y, osc.z, osc.w };
    float xva[4] = { xv.x, xv.y, xv.z, xv.w };
    float oa[4];
#pragma unroll
    for (int c = 0; c < 4; ++c) {
      float th = fmaf(cxa[c], 1.f / (1.f + fabsf(woa[c])), boa[c]) + sphi;
      float f = fract1(th * INV2PI_F);
      float ao = osa[c] * (cos_rev(f) + sin_rev(f));
      float r = rr[c];
      float sil = r / (1.f + __expf(-r));
      oa[c] = fmaf(as, ao, fmaf(rs, sil, xva[c]));
    }
    *(float4*)(xout + T * cD + di) = make_float4(oa[0], oa[1], oa[2], oa[3]);
  }
}

// ---------------- pack final x into MFMA A-frag order (bf16) ----------------
// Xpk[((mb*4 + ks)*64 + lane)*8 + j] = X[mb*16 + (lane&15)][ks*32 + (lane>>4)*8 + j]
__global__ void k_pack(const float* __restrict__ X, unsigned short* __restrict__ Xpk) {
  int tid = blockIdx.x * 256 + threadIdx.x;        // 8192 = 32 mb * 4 ks * 64 lane
  int lane = tid & 63, ks = (tid >> 6) & 3, mb = tid >> 8;
  int row = mb * 16 + (lane & 15);
  int k0 = ks * 32 + (lane >> 4) * 8;
  const float* src = X + row * cD + k0;
  ushort4 lo = { f2bf(src[0]), f2bf(src[1]), f2bf(src[2]), f2bf(src[3]) };
  ushort4 hi = { f2bf(src[4]), f2bf(src[5]), f2bf(src[6]), f2bf(src[7]) };
  unsigned short* dst = Xpk + tid * 8;
  *(ushort4*)dst = lo;
  *(ushort4*)(dst + 4) = hi;
}

// ---------------- final logits GEMM: block = all 512 m x 64 v ---------------
// grid 786, 256 threads (4 waves); wave = 128 m-rows x 64 v; W fetched once.
__global__ __launch_bounds__(256) void k_gemm(const unsigned short* __restrict__ Xpk,
                                              const float* __restrict__ W,
                                              float* __restrict__ out) {
  __shared__ __align__(16) unsigned short Wl[64 * 128];   // 16KB bf16, XOR-swizzled
  __shared__ __align__(16) float Cw[4][16 * 64];          // 16KB per-wave C staging
  int t = threadIdx.x;
  int v0 = blockIdx.x * 64;
  // stage W tile (64 v-rows x 128 k), f32 -> bf16, swizzled
#pragma unroll
  for (int i = 0; i < 8; ++i) {
    int idx = t + i * 256;            // 2048 = 64 rows * 32 col4-groups
    int row = idx >> 5, c4 = idx & 31;
    int v = v0 + row;
    float4 wv = make_float4(0.f, 0.f, 0.f, 0.f);
    if (v < cV) wv = *(const float4*)(W + (size_t)v * cD + c4 * 4);
    ushort4 b4 = { f2bf(wv.x), f2bf(wv.y), f2bf(wv.z), f2bf(wv.w) };
    int byte = (row * 256 + c4 * 8) ^ ((row & 7) << 4);
    *(ushort4*)((char*)Wl + byte) = b4;
  }
  int wid = t >> 6, lane = t & 63;
  int lr = lane & 15, lk = lane >> 4;
  const bf16x8* Ap = (const bf16x8*)Xpk;           // [(mb*4+ks)*64 + lane]
  bf16x8 aCur[8], aNxt[8];
#pragma unroll
  for (int fm = 0; fm < 8; ++fm)
    aCur[fm] = Ap[((wid * 8 + fm) * 4 + 0) * 64 + lane];
  f32x4 acc[8][4];
#pragma unroll
  for (int fm = 0; fm < 8; ++fm)
#pragma unroll
    for (int fv = 0; fv < 4; ++fv) acc[fm][fv] = (f32x4){0.f, 0.f, 0.f, 0.f};
  __syncthreads();
#pragma unroll
  for (int ks = 0; ks < 4; ++ks) {
    if (ks < 3) {
#pragma unroll
      for (int fm = 0; fm < 8; ++fm)
        aNxt[fm] = Ap[((wid * 8 + fm) * 4 + ks + 1) * 64 + lane];
    }
    bf16x8 b[4];
#pragma unroll
    for (int fv = 0; fv < 4; ++fv) {
      int v = fv * 16 + lr;
      int byte = (v * 256 + ks * 64 + lk * 16) ^ ((v & 7) << 4);
      b[fv] = *(const bf16x8*)((const char*)Wl + byte);
    }
#pragma unroll
    for (int fm = 0; fm < 8; ++fm)
#pragma unroll
      for (int fv = 0; fv < 4; ++fv)
        acc[fm][fv] = __builtin_amdgcn_mfma_f32_16x16x32_bf16(aCur[fm], b[fv], acc[fm][fv], 0, 0, 0);
#pragma unroll
    for (int fm = 0; fm < 8; ++fm) aCur[fm] = aNxt[fm];
  }
  // epilogue: per-wave LDS transpose -> float4 stores (256B row segments)
  bool full = (v0 + 64 <= cV);
  float* Cp = Cw[wid];
#pragma unroll
  for (int fm = 0; fm < 8; ++fm) {
#pragma unroll
    for (int fv = 0; fv < 4; ++fv) {
#pragma unroll
      for (int r = 0; r < 4; ++r) {
        int rowl = lk * 4 + r;
        int colw = fv * 16 + lr;
        Cp[(rowl * 64 + colw) ^ (((rowl >> 2) & 1) << 4)] = acc[fm][fv][r];
      }
    }
    int grow0 = wid * 128 + fm * 16;
#pragma unroll
    for (int r2 = 0; r2 < 4; ++r2) {
      int rowl = r2 * 4 + lk;
      float4 cv = *(const float4*)&Cp[(rowl * 64 + lr * 4) ^ ((r2 & 1) << 4)];
      int grow = grow0 + rowl;
      if (full) {
        *(float4*)(out + (size_t)grow * cV + v0 + lr * 4) = cv;
      } else {
        int cbase = v0 + lr * 4;
        float ca[4] = { cv.x, cv.y, cv.z, cv.w };
#pragma unroll
        for (int j = 0; j < 4; ++j)
          if (cbase + j < cV) out[(size_t)grow * cV + cbase + j] = ca[j];
      }
    }
  }
}

extern "C" void kernel_launch(void* const* d_in, const int* in_sizes, int n_in,
                              void* d_out, int out_size, void* d_ws, size_t ws_size,
                              hipStream_t stream) {
  const int*   tokens    = (const int*)d_in[0];
  const float* emb       = (const float*)d_in[1];
  const float* wq        = (const float*)d_in[2];
  const float* bq        = (const float*)d_in[3];
  const float* wk        = (const float*)d_in[4];
  const float* bk        = (const float*)d_in[5];
  const float* w_out     = (const float*)d_in[6];
  const float* b_out     = (const float*)d_in[7];
  const float* out_scale = (const float*)d_in[8];
  const float* Wf        = (const float*)d_in[9];
  const float* Bf        = (const float*)d_in[10];
  const float* pr        = (const float*)d_in[11];
  const float* pi        = (const float*)d_in[12];
  const float* attn_s    = (const float*)d_in[13];
  const float* res_s     = (const float*)d_in[14];
  const float* out_proj  = (const float*)d_in[15];
  float* out = (float*)d_out;
  float* ws  = (float*)d_ws;

  float*  states = ws;                 // 65536
  float*  x1     = ws + 65536;         // 65536
  float*  x2     = ws + 131072;        // 65536
  float*  ctx    = ws + 196608;        // 65536
  float2* mc     = (float2*)(ws + 262144); // 131072 floats
  float*  Q      = ws + 393216;        // 131072
  float*  Kt     = ws + 524288;        // 131072
  float*  U      = ws + 655360;        // 262144
  float*  Vv     = ws + 917504;        // 262144
  float*  pTR    = ws + 1179648;       // 131072
  float*  pTI    = ws + 1310720;       // 131072
  unsigned short* Xpk = (unsigned short*)(ws + 1441792); // 65536 ushorts (128KB)

  k_prep_mc<<<256, 256, 0, stream>>>(tokens, emb, mc);
  k_transpose_proj<<<512, 256, 0, stream>>>(pr, pi, pTR, pTI);
  k_scan<<<1, 256, 0, stream>>>(mc, states);

  const float* xin = states;
  float* xouts[2] = { x1, x2 };
  for (int l = 0; l < 2; ++l) {
    k_qk<<<256, 256, 0, stream>>>(xin, states, wq + l * 128, bq + l * 128,
                                  wk + l * 128, bk + l * 128, Q, Kt);
    k_attn<<<512, 256, 0, stream>>>(Q, Kt, states, ctx);
    k_fsum<<<256, 512, 0, stream>>>(xin, Wf + l * 65536, Bf + l * 65536, U, Vv);
    k_res<<<256, 128, 0, stream>>>(U, Vv, pTR, pTI, ctx, xin, w_out, b_out, out_scale,
                                   attn_s, res_s, l, xouts[l]);
    xin = xouts[l];
  }
  k_pack<<<32, 256, 0, stream>>>(x2, Xpk);
  k_gemm<<<(cV + 63) / 64, 256, 0, stream>>>(Xpk, out_proj, out);
}

// Round 3
// 188.758 us; speedup vs baseline: 1.2743x; 1.2312x over previous
//
#include <hip/hip_runtime.h>
#include <hip/hip_bf16.h>

using bf16x8 = __attribute__((ext_vector_type(8))) short;
using f32x4  = __attribute__((ext_vector_type(4))) float;

constexpr int cV  = 50257;
constexpr int cD  = 128;
constexpr int cN  = 512;
constexpr int cS  = 256;

#define PHI_F    1.6180339887498949f
#define INV2PI_F 0.15915494309189535f
#define SQRT2_F  1.4142135623730951f

__device__ __forceinline__ float fract1(float x) { return x - floorf(x); }

#if __has_builtin(__builtin_amdgcn_sinf)
__device__ __forceinline__ float sin_rev(float r) { return __builtin_amdgcn_sinf(r); }   // sin(2*pi*r)
__device__ __forceinline__ float cos_rev(float r) { return __builtin_amdgcn_cosf(r); }   // cos(2*pi*r)
#else
__device__ __forceinline__ float sin_rev(float r) { return __sinf(r * 6.2831853071795865f); }
__device__ __forceinline__ float cos_rev(float r) { return __cosf(r * 6.2831853071795865f); }
#endif

__device__ __forceinline__ unsigned short f2bf(float f) {
  unsigned u = __float_as_uint(f);
  unsigned r = (u + 0x7FFFu + ((u >> 16) & 1u)) >> 16;
  return (unsigned short)r;
}

// ---------------- setup: mc prep (blocks 0-255) + proj transpose (256-767) ---
__global__ void k_setup(const int* __restrict__ tokens, const float* __restrict__ emb,
                        float2* __restrict__ mc,
                        const float* __restrict__ pr, const float* __restrict__ pi,
                        float* __restrict__ pTR, float* __restrict__ pTI) {
  int blk = blockIdx.x;
  if (blk < 256) {
    int idx = blk * 256 + threadIdx.x;             // 65536 = S * (B*D)
    int t = idx & 255, s = idx >> 8;
    int b = t >> 7, d = t & 127;
    int tok = tokens[b * cS + s];
    float w  = emb[tok * (2 * cD) + d];
    float be = emb[tok * (2 * cD) + cD + d];
    float m2 = SQRT2_F * INV2PI_F / (1.f + fabsf(w));
    float c  = fmaf((float)s, PHI_F, be) * INV2PI_F + 0.125f;
    mc[idx] = make_float2(m2, c);
  } else {
    int idx = (blk - 256) * 256 + threadIdx.x;     // L*N*D = 131072
    int l = idx >> 16, rem = idx & 65535;
    int n = rem >> 7, d = rem & 127;
    int src = (l * cD + d) * cN + n;
    pTR[idx] = pr[src];
    pTI[idx] = pi[src];
  }
}

// ---------------- sequential scan -------------------------------------------
__global__ void k_scan(const float2* __restrict__ mc, float* __restrict__ states) {
  int t = threadIdx.x;                              // 256 = B*D
  int b = t >> 7, d = t & 127;
  float2 buf[8];
#pragma unroll
  for (int i = 0; i < 8; ++i) buf[i] = mc[i * 256 + t];
  float sv = 0.f;
  float* out = states + (b * cS) * cD + d;
#pragma unroll 8
  for (int s = 0; s < cS; ++s) {
    float2 v = buf[s & 7];
    if (s + 8 < cS) buf[s & 7] = mc[(s + 8) * 256 + t];
    float r = fmaf(sv, v.x, v.y);
    sv = sin_rev(fract1(r));
    out[s * cD] = sv * SQRT2_F;
  }
}

// ---------------- fused per-layer: attn (blocks 0-255) || fsum (256-511) ----
__global__ __launch_bounds__(512) void k_layer(const float* __restrict__ x, const float* __restrict__ states,
                                               const float* __restrict__ wq, const float* __restrict__ bq,
                                               const float* __restrict__ wk, const float* __restrict__ bk,
                                               const float* __restrict__ Wf, const float* __restrict__ Bf,
                                               float* __restrict__ ctx, float* __restrict__ U, float* __restrict__ Vv) {
  int blk = blockIdx.x;
  if (blk < 256) {
    // ---- attention: 2 q-rows per block (sub 0/1), Q and K recomputed ----
    __shared__ __align__(16) float qrow[2][256];    // [sub][hd]=cos, [sub][128+hd]=sin
    __shared__ float Psum[2][256];
    __shared__ float redm[2][4], reds[2][4];
    __shared__ float cred[2][256];
    __shared__ __align__(16) float rkl[128], bkl[128];
    int b = blk >> 7, qp = blk & 127;
    int sub = threadIdx.x >> 8;
    int t = threadIdx.x & 255;
    int q = qp * 2 + sub;
    if (threadIdx.x < 128) {                        // K params (shared by both subs)
      int hd = threadIdx.x;
      rkl[hd] = INV2PI_F / (1.f + fabsf(wk[hd]));
      bkl[hd] = bk[hd] * INV2PI_F;
    }
    if (t < 128) {                                  // Q row for this sub
      int hd = t;
      float rq = 1.f / (1.f + fabsf(wq[hd]));
      float thq = fmaf(x[(b * cS + q) * cD + hd], rq, fmaf((float)q, PHI_F, bq[hd])) * INV2PI_F;
      float fq = fract1(thq);
      qrow[sub][hd]       = cos_rev(fq);
      qrow[sub][128 + hd] = sin_rev(fq);
    }
    Psum[sub][t] = 0.f;
    __syncthreads();
    bool act = (t <= q);
    float sc[8];
    const float4* Sr = (const float4*)(states + (b * cS + t) * cD);
#pragma unroll
    for (int h = 0; h < 8; ++h) {
      float sacc = 0.f;
#pragma unroll
      for (int j = 0; j < 4; ++j) {
        float4 sv4 = Sr[h * 4 + j];
        int hd = h * 16 + j * 4;
        float sva[4] = { sv4.x, sv4.y, sv4.z, sv4.w };
#pragma unroll
        for (int c = 0; c < 4; ++c) {
          float f = fract1(fmaf(sva[c], rkl[hd + c], bkl[hd + c]));
          float ck = cos_rev(f), sk = sin_rev(f);
          sacc = fmaf(qrow[sub][hd + c], ck, fmaf(qrow[sub][128 + hd + c], sk, sacc));
        }
      }
      sc[h] = act ? sacc * 0.17677669529663689f : -3.0e38f;  // 1/sqrt(2*DH)
    }
    int wid = t >> 6;
    for (int h = 0; h < 8; ++h) {
      float v = sc[h];
#pragma unroll
      for (int off = 32; off; off >>= 1) v = fmaxf(v, __shfl_xor(v, off, 64));
      if ((t & 63) == 0) redm[sub][wid] = v;
      __syncthreads();
      float m = fmaxf(fmaxf(redm[sub][0], redm[sub][1]), fmaxf(redm[sub][2], redm[sub][3]));
      float p = act ? __expf(sc[h] - m) : 0.f;
      float ps = p;
#pragma unroll
      for (int off = 32; off; off >>= 1) ps += __shfl_xor(ps, off, 64);
      if ((t & 63) == 0) reds[sub][wid] = ps;
      __syncthreads();
      float tot = reds[sub][0] + reds[sub][1] + reds[sub][2] + reds[sub][3];
      Psum[sub][t] += p / tot;
    }
    __syncthreads();
    int d = t & 127, half = t >> 7;
    float acc = 0.f;
    int k0 = half * 128;
    int kend = min(k0 + 128, q + 1);
    for (int kk = k0; kk < kend; ++kk)
      acc = fmaf(Psum[sub][kk], states[(b * cS + kk) * cD + d], acc);
    cred[sub][t] = acc;
    __syncthreads();
    if (half == 0) ctx[(b * cS + q) * cD + d] = cred[sub][t] + cred[sub][t + 128];
  } else {
    // ---- fsum: th_f cos/sin sums ----
    int fblk = blk - 256;
    int ns = fblk & 15, tg = fblk >> 4;
    constexpr int P = 130;
    __shared__ __align__(16) float finv[32 * P];
    __shared__ __align__(16) float fb[32 * P];
    __shared__ __align__(16) float xl[32 * 128];
    int t = threadIdx.x;
#pragma unroll
    for (int i = 0; i < 8; ++i) {
      int idx = t + i * 512;
      int rl = idx >> 7, d = idx & 127;
      int g = (ns * 32 + rl) * cD + d;
      finv[rl * P + d] = INV2PI_F / (1.f + fabsf(Wf[g]));
      fb[rl * P + d]   = Bf[g] * INV2PI_F;
      xl[idx] = x[(tg * 32 + rl) * cD + d];
    }
    __syncthreads();
    int nl = t & 31, tli = t >> 5;
#pragma unroll
    for (int p = 0; p < 2; ++p) {
      int tl = p * 16 + tli;
      int T = tg * 32 + tl;
      float srev = (float)(T & 255) * INV2PI_F;
      float uc = 0.f, us = 0.f;
      const float* fi  = finv + nl * P;
      const float* fbp = fb + nl * P;
      const float* xr  = xl + tl * 128;
#pragma unroll 4
      for (int d = 0; d < cD; d += 2) {
        float2 fiv = *(const float2*)(fi + d);
        float2 fbv = *(const float2*)(fbp + d);
        float2 xv  = *(const float2*)(xr + d);
        float f0 = fract1(fmaf(xv.x, fiv.x, fbv.x) + srev);
        float f1 = fract1(fmaf(xv.y, fiv.y, fbv.y) + srev);
        uc += cos_rev(f0);
        us += sin_rev(f0);
        uc += cos_rev(f1);
        us += sin_rev(f1);
      }
      U[T * cN + ns * 32 + nl]  = uc;
      Vv[T * cN + ns * 32 + nl] = us;
    }
  }
}

// ---------------- res projection + attn-out + combine (per layer) ------------
// grid 128 x 256 thr; block = 4 tokens; thread: d4=t&31, g=t>>5 -> tok=g&3, nh=g>>2
__global__ __launch_bounds__(256) void k_res(const float* __restrict__ U, const float* __restrict__ Vv,
                                             const float* __restrict__ pTR, const float* __restrict__ pTI,
                                             const float* __restrict__ ctx, const float* __restrict__ x,
                                             const float* __restrict__ w_out, const float* __restrict__ b_out,
                                             const float* __restrict__ out_scale,
                                             const float* __restrict__ attn_scale, const float* __restrict__ res_scale,
                                             int l, float* __restrict__ xout, unsigned short* __restrict__ xbf) {
  int blk = blockIdx.x;
  int t = threadIdx.x;
  __shared__ __align__(16) float uv[4][512][2];     // 16KB
  __shared__ __align__(16) float4 part[128];
#pragma unroll
  for (int i = 0; i < 8; ++i) {
    int idx = t + i * 256;                          // 2048 = 4 tok * 512 n
    int tok = idx >> 9, n = idx & 511;
    uv[tok][n][0] = U[(blk * 4 + tok) * cN + n];
    uv[tok][n][1] = Vv[(blk * 4 + tok) * cN + n];
  }
  __syncthreads();
  int d4 = t & 31, g = t >> 5, tok = g & 3, nh = g >> 2;
  int T = blk * 4 + tok, s = T & 255;
  float a0 = 0.f, a1 = 0.f, a2 = 0.f, a3 = 0.f;
  const float* prB = pTR + (size_t)(l * cN) * cD + d4 * 4;
  const float* piB = pTI + (size_t)(l * cN) * cD + d4 * 4;
  int nEnd = nh * 256 + 256;
  for (int n = nh * 256; n < nEnd; ++n) {
    float4 pr = *(const float4*)(prB + n * cD);
    float4 pi = *(const float4*)(piB + n * cD);
    float2 w = *(const float2*)&uv[tok][n][0];
    a0 = fmaf(w.x, pr.x, fmaf(w.y, pi.x, a0));
    a1 = fmaf(w.x, pr.y, fmaf(w.y, pi.y, a1));
    a2 = fmaf(w.x, pr.z, fmaf(w.y, pi.z, a2));
    a3 = fmaf(w.x, pr.w, fmaf(w.y, pi.w, a3));
  }
  if (nh == 1) part[tok * 32 + d4] = make_float4(a0, a1, a2, a3);
  __syncthreads();
  if (nh == 0) {
    float4 p2 = part[tok * 32 + d4];
    float rr[4] = { a0 + p2.x, a1 + p2.y, a2 + p2.z, a3 + p2.w };
    int di = d4 * 4;
    float4 cx  = *(const float4*)(ctx + T * cD + di);
    float4 wo  = *(const float4*)(w_out + l * cD + di);
    float4 bo  = *(const float4*)(b_out + l * cD + di);
    float4 osc = *(const float4*)(out_scale + l * cD + di);
    float4 xv  = *(const float4*)(x + T * cD + di);
    float as = attn_scale[l], rs = res_scale[l];
    float sphi = (float)s * PHI_F;
    float cxa[4] = { cx.x, cx.y, cx.z, cx.w };
    float woa[4] = { wo.x, wo.y, wo.z, wo.w };
    float boa[4] = { bo.x, bo.y, bo.z, bo.w };
    float osa[4] = { osc.x, osc.y, osc.z, osc.w };
    float xva[4] = { xv.x, xv.y, xv.z, xv.w };
    float oa[4];
#pragma unroll
    for (int c = 0; c < 4; ++c) {
      float th = fmaf(cxa[c], 1.f / (1.f + fabsf(woa[c])), boa[c]) + sphi;
      float f = fract1(th * INV2PI_F);
      float ao = osa[c] * (cos_rev(f) + sin_rev(f));
      float r = rr[c];
      float sil = r / (1.f + __expf(-r));
      oa[c] = fmaf(as, ao, fmaf(rs, sil, xva[c]));
    }
    *(float4*)(xout + T * cD + di) = make_float4(oa[0], oa[1], oa[2], oa[3]);
    if (xbf) {
      ushort4 b4 = { f2bf(oa[0]), f2bf(oa[1]), f2bf(oa[2]), f2bf(oa[3]) };
      *(ushort4*)(xbf + T * cD + di) = b4;
    }
  }
}

// ---------------- final logits GEMM: block = all 512 m x 64 v ---------------
// grid 786, 256 threads (4 waves); wave = 128 m-rows x 64 v; W fetched once.
__global__ __launch_bounds__(256) void k_gemm(const unsigned short* __restrict__ Xbf,
                                              const float* __restrict__ W,
                                              float* __restrict__ out) {
  __shared__ __align__(16) unsigned short Wl[64 * 128];   // 16KB bf16, XOR-swizzled
  __shared__ __align__(16) float Cw[4][16 * 64];          // 16KB per-wave C staging
  int t = threadIdx.x;
  int v0 = blockIdx.x * 64;
#pragma unroll
  for (int i = 0; i < 8; ++i) {
    int idx = t + i * 256;            // 2048 = 64 rows * 32 col4-groups
    int row = idx >> 5, c4 = idx & 31;
    int v = v0 + row;
    float4 wv = make_float4(0.f, 0.f, 0.f, 0.f);
    if (v < cV) wv = *(const float4*)(W + (size_t)v * cD + c4 * 4);
    ushort4 b4 = { f2bf(wv.x), f2bf(wv.y), f2bf(wv.z), f2bf(wv.w) };
    int byte = (row * 256 + c4 * 8) ^ ((row & 7) << 4);
    *(ushort4*)((char*)Wl + byte) = b4;
  }
  int wid = t >> 6, lane = t & 63;
  int lr = lane & 15, lk = lane >> 4;
  // A-frag rows for this wave: wid*128 + fm*16 + lr ; k chunk: ks*32 + lk*8
  f32x4 acc[8][4];
#pragma unroll
  for (int fm = 0; fm < 8; ++fm)
#pragma unroll
    for (int fv = 0; fv < 4; ++fv) acc[fm][fv] = (f32x4){0.f, 0.f, 0.f, 0.f};
  __syncthreads();
#pragma unroll
  for (int ks = 0; ks < 4; ++ks) {
    bf16x8 a[8];
#pragma unroll
    for (int fm = 0; fm < 8; ++fm) {
      int row = wid * 128 + fm * 16 + lr;
      a[fm] = *(const bf16x8*)(Xbf + row * cD + ks * 32 + lk * 8);
    }
    bf16x8 bfr[4];
#pragma unroll
    for (int fv = 0; fv < 4; ++fv) {
      int v = fv * 16 + lr;
      int byte = (v * 256 + ks * 64 + lk * 16) ^ ((v & 7) << 4);
      bfr[fv] = *(const bf16x8*)((const char*)Wl + byte);
    }
#pragma unroll
    for (int fm = 0; fm < 8; ++fm)
#pragma unroll
      for (int fv = 0; fv < 4; ++fv)
        acc[fm][fv] = __builtin_amdgcn_mfma_f32_16x16x32_bf16(a[fm], bfr[fv], acc[fm][fv], 0, 0, 0);
  }
  // epilogue: per-wave LDS transpose -> float4 stores (256B row segments)
  bool full = (v0 + 64 <= cV);
  float* Cp = Cw[wid];
#pragma unroll
  for (int fm = 0; fm < 8; ++fm) {
#pragma unroll
    for (int fv = 0; fv < 4; ++fv) {
#pragma unroll
      for (int r = 0; r < 4; ++r) {
        int rowl = lk * 4 + r;
        int colw = fv * 16 + lr;
        Cp[(rowl * 64 + colw) ^ (((rowl >> 2) & 1) << 4)] = acc[fm][fv][r];
      }
    }
    int grow0 = wid * 128 + fm * 16;
#pragma unroll
    for (int r2 = 0; r2 < 4; ++r2) {
      int rowl = r2 * 4 + lk;
      float4 cv = *(const float4*)&Cp[(rowl * 64 + lr * 4) ^ ((r2 & 1) << 4)];
      int grow = grow0 + rowl;
      if (full) {
        *(float4*)(out + (size_t)grow * cV + v0 + lr * 4) = cv;
      } else {
        int cbase = v0 + lr * 4;
        float ca[4] = { cv.x, cv.y, cv.z, cv.w };
#pragma unroll
        for (int j = 0; j < 4; ++j)
          if (cbase + j < cV) out[(size_t)grow * cV + cbase + j] = ca[j];
      }
    }
  }
}

extern "C" void kernel_launch(void* const* d_in, const int* in_sizes, int n_in,
                              void* d_out, int out_size, void* d_ws, size_t ws_size,
                              hipStream_t stream) {
  const int*   tokens    = (const int*)d_in[0];
  const float* emb       = (const float*)d_in[1];
  const float* wq        = (const float*)d_in[2];
  const float* bq        = (const float*)d_in[3];
  const float* wk        = (const float*)d_in[4];
  const float* bk        = (const float*)d_in[5];
  const float* w_out     = (const float*)d_in[6];
  const float* b_out     = (const float*)d_in[7];
  const float* out_scale = (const float*)d_in[8];
  const float* Wf        = (const float*)d_in[9];
  const float* Bf        = (const float*)d_in[10];
  const float* pr        = (const float*)d_in[11];
  const float* pi        = (const float*)d_in[12];
  const float* attn_s    = (const float*)d_in[13];
  const float* res_s     = (const float*)d_in[14];
  const float* out_proj  = (const float*)d_in[15];
  float* out = (float*)d_out;
  float* ws  = (float*)d_ws;

  float*  states = ws;                     // 65536
  float*  x1     = ws + 65536;             // 65536
  float*  x2     = ws + 131072;            // 65536
  float*  ctx    = ws + 196608;            // 65536
  float2* mc     = (float2*)(ws + 262144); // 131072 floats
  float*  U      = ws + 393216;            // 262144
  float*  Vv     = ws + 655360;            // 262144
  float*  pTR    = ws + 917504;            // 131072
  float*  pTI    = ws + 1048576;           // 131072
  unsigned short* X2bf = (unsigned short*)(ws + 1179648); // 65536 ushorts

  k_setup<<<768, 256, 0, stream>>>(tokens, emb, mc, pr, pi, pTR, pTI);
  k_scan<<<1, 256, 0, stream>>>(mc, states);

  const float* xin = states;
  float* xouts[2] = { x1, x2 };
  for (int l = 0; l < 2; ++l) {
    k_layer<<<512, 512, 0, stream>>>(xin, states, wq + l * 128, bq + l * 128,
                                     wk + l * 128, bk + l * 128,
                                     Wf + l * 65536, Bf + l * 65536, ctx, U, Vv);
    k_res<<<128, 256, 0, stream>>>(U, Vv, pTR, pTI, ctx, xin, w_out, b_out, out_scale,
                                   attn_s, res_s, l, xouts[l],
                                   (l == 1) ? X2bf : (unsigned short*)nullptr);
    xin = xouts[l];
  }
  k_gemm<<<(cV + 63) / 64, 256, 0, stream>>>(X2bf, out_proj, out);
}

// Round 4
// 179.651 us; speedup vs baseline: 1.3389x; 1.0507x over previous
//
#include <hip/hip_runtime.h>
#include <hip/hip_bf16.h>

using bf16x8 = __attribute__((ext_vector_type(8))) short;
using f32x4  = __attribute__((ext_vector_type(4))) float;

constexpr int cV  = 50257;
constexpr int cVp = 50304;          // padded rows for bf16 W (786*64)
constexpr int cD  = 128;
constexpr int cN  = 512;
constexpr int cS  = 256;

#define PHI_F    1.6180339887498949f
#define INV2PI_F 0.15915494309189535f
#define SQRT2_F  1.4142135623730951f

__device__ __forceinline__ float fract1(float x) { return x - floorf(x); }

#if __has_builtin(__builtin_amdgcn_sinf)
__device__ __forceinline__ float sin_rev(float r) { return __builtin_amdgcn_sinf(r); }   // sin(2*pi*r)
__device__ __forceinline__ float cos_rev(float r) { return __builtin_amdgcn_cosf(r); }   // cos(2*pi*r)
#else
__device__ __forceinline__ float sin_rev(float r) { return __sinf(r * 6.2831853071795865f); }
__device__ __forceinline__ float cos_rev(float r) { return __cosf(r * 6.2831853071795865f); }
#endif

__device__ __forceinline__ unsigned short f2bf(float f) {
  unsigned u = __float_as_uint(f);
  unsigned r = (u + 0x7FFFu + ((u >> 16) & 1u)) >> 16;
  return (unsigned short)r;
}

// ------ setup: mc prep (0-255) + proj transpose (256-767) + W bf16 pack (768+) ------
__global__ void k_setup(const int* __restrict__ tokens, const float* __restrict__ emb,
                        float2* __restrict__ mc,
                        const float* __restrict__ pr, const float* __restrict__ pi,
                        float* __restrict__ pTR, float* __restrict__ pTI,
                        const float* __restrict__ W, unsigned short* __restrict__ Wbf) {
  int blk = blockIdx.x;
  if (blk < 256) {
    int idx = blk * 256 + threadIdx.x;             // 65536 = S * (B*D)
    int t = idx & 255, s = idx >> 8;
    int b = t >> 7, d = t & 127;
    int tok = tokens[b * cS + s];
    float w  = emb[tok * (2 * cD) + d];
    float be = emb[tok * (2 * cD) + cD + d];
    float m2 = SQRT2_F * INV2PI_F / (1.f + fabsf(w));
    float c  = fmaf((float)s, PHI_F, be) * INV2PI_F + 0.125f;
    mc[idx] = make_float2(m2, c);
  } else if (blk < 768) {
    int idx = (blk - 256) * 256 + threadIdx.x;     // L*N*D = 131072
    int l = idx >> 16, rem = idx & 65535;
    int n = rem >> 7, d = rem & 127;
    int src = (l * cD + d) * cN + n;
    pTR[idx] = pr[src];
    pTI[idx] = pi[src];
  } else {
    int idx = (blk - 768) * 256 + threadIdx.x;     // 804864 = 50304 rows * 16
    int row = idx >> 4, c0 = (idx & 15) * 8;
    ushort4 o0 = {0,0,0,0}, o1 = {0,0,0,0};
    if (row < cV) {
      float4 w0 = *(const float4*)(W + (size_t)row * cD + c0);
      float4 w1 = *(const float4*)(W + (size_t)row * cD + c0 + 4);
      o0 = { f2bf(w0.x), f2bf(w0.y), f2bf(w0.z), f2bf(w0.w) };
      o1 = { f2bf(w1.x), f2bf(w1.y), f2bf(w1.z), f2bf(w1.w) };
    }
    unsigned short* dst = Wbf + (size_t)row * cD + c0;
    *(ushort4*)dst = o0;
    *(ushort4*)(dst + 4) = o1;
  }
}

// ---------------- sequential scan -------------------------------------------
__global__ void k_scan(const float2* __restrict__ mc, float* __restrict__ states) {
  int t = threadIdx.x;                              // 256 = B*D
  int b = t >> 7, d = t & 127;
  float2 buf[8];
#pragma unroll
  for (int i = 0; i < 8; ++i) buf[i] = mc[i * 256 + t];
  float sv = 0.f;
  float* out = states + (b * cS) * cD + d;
#pragma unroll 8
  for (int s = 0; s < cS; ++s) {
    float2 v = buf[s & 7];
    if (s + 8 < cS) buf[s & 7] = mc[(s + 8) * 256 + t];
    float r = fmaf(sv, v.x, v.y);
    sv = sin_rev(fract1(r));
    out[s * cD] = sv * SQRT2_F;
  }
}

// ---------------- fused per-layer: attn (blocks 0-255) || fsum (256-511) ----
__global__ __launch_bounds__(512) void k_layer(const float* __restrict__ x, const float* __restrict__ states,
                                               const float* __restrict__ wq, const float* __restrict__ bq,
                                               const float* __restrict__ wk, const float* __restrict__ bk,
                                               const float* __restrict__ Wf, const float* __restrict__ Bf,
                                               float* __restrict__ ctx, float* __restrict__ U, float* __restrict__ Vv) {
  int blk = blockIdx.x;
  if (blk < 256) {
    __shared__ __align__(16) float qrow[2][256];
    __shared__ float Psum[2][256];
    __shared__ float redm[2][4], reds[2][4];
    __shared__ float cred[2][256];
    __shared__ __align__(16) float rkl[128], bkl[128];
    int b = blk >> 7, qp = blk & 127;
    int sub = threadIdx.x >> 8;
    int t = threadIdx.x & 255;
    int q = qp * 2 + sub;
    if (threadIdx.x < 128) {
      int hd = threadIdx.x;
      rkl[hd] = INV2PI_F / (1.f + fabsf(wk[hd]));
      bkl[hd] = bk[hd] * INV2PI_F;
    }
    if (t < 128) {
      int hd = t;
      float rq = 1.f / (1.f + fabsf(wq[hd]));
      float thq = fmaf(x[(b * cS + q) * cD + hd], rq, fmaf((float)q, PHI_F, bq[hd])) * INV2PI_F;
      float fq = fract1(thq);
      qrow[sub][hd]       = cos_rev(fq);
      qrow[sub][128 + hd] = sin_rev(fq);
    }
    Psum[sub][t] = 0.f;
    __syncthreads();
    bool act = (t <= q);
    float sc[8];
    const float4* Sr = (const float4*)(states + (b * cS + t) * cD);
#pragma unroll
    for (int h = 0; h < 8; ++h) {
      float sacc = 0.f;
#pragma unroll
      for (int j = 0; j < 4; ++j) {
        float4 sv4 = Sr[h * 4 + j];
        int hd = h * 16 + j * 4;
        float sva[4] = { sv4.x, sv4.y, sv4.z, sv4.w };
#pragma unroll
        for (int c = 0; c < 4; ++c) {
          float f = fract1(fmaf(sva[c], rkl[hd + c], bkl[hd + c]));
          float ck = cos_rev(f), sk = sin_rev(f);
          sacc = fmaf(qrow[sub][hd + c], ck, fmaf(qrow[sub][128 + hd + c], sk, sacc));
        }
      }
      sc[h] = act ? sacc * 0.17677669529663689f : -3.0e38f;
    }
    int wid = t >> 6;
    for (int h = 0; h < 8; ++h) {
      float v = sc[h];
#pragma unroll
      for (int off = 32; off; off >>= 1) v = fmaxf(v, __shfl_xor(v, off, 64));
      if ((t & 63) == 0) redm[sub][wid] = v;
      __syncthreads();
      float m = fmaxf(fmaxf(redm[sub][0], redm[sub][1]), fmaxf(redm[sub][2], redm[sub][3]));
      float p = act ? __expf(sc[h] - m) : 0.f;
      float ps = p;
#pragma unroll
      for (int off = 32; off; off >>= 1) ps += __shfl_xor(ps, off, 64);
      if ((t & 63) == 0) reds[sub][wid] = ps;
      __syncthreads();
      float tot = reds[sub][0] + reds[sub][1] + reds[sub][2] + reds[sub][3];
      Psum[sub][t] += p / tot;
    }
    __syncthreads();
    int d = t & 127, half = t >> 7;
    float acc = 0.f;
    int k0 = half * 128;
    int kend = min(k0 + 128, q + 1);
    for (int kk = k0; kk < kend; ++kk)
      acc = fmaf(Psum[sub][kk], states[(b * cS + kk) * cD + d], acc);
    cred[sub][t] = acc;
    __syncthreads();
    if (half == 0) ctx[(b * cS + q) * cD + d] = cred[sub][t] + cred[sub][t + 128];
  } else {
    int fblk = blk - 256;
    int ns = fblk & 15, tg = fblk >> 4;
    constexpr int P = 130;
    __shared__ __align__(16) float finv[32 * P];
    __shared__ __align__(16) float fb[32 * P];
    __shared__ __align__(16) float xl[32 * 128];
    int t = threadIdx.x;
#pragma unroll
    for (int i = 0; i < 8; ++i) {
      int idx = t + i * 512;
      int rl = idx >> 7, d = idx & 127;
      int g = (ns * 32 + rl) * cD + d;
      finv[rl * P + d] = INV2PI_F / (1.f + fabsf(Wf[g]));
      fb[rl * P + d]   = Bf[g] * INV2PI_F;
      xl[idx] = x[(tg * 32 + rl) * cD + d];
    }
    __syncthreads();
    int nl = t & 31, tli = t >> 5;
#pragma unroll
    for (int p = 0; p < 2; ++p) {
      int tl = p * 16 + tli;
      int T = tg * 32 + tl;
      float srev = (float)(T & 255) * INV2PI_F;
      float uc = 0.f, us = 0.f;
      const float* fi  = finv + nl * P;
      const float* fbp = fb + nl * P;
      const float* xr  = xl + tl * 128;
#pragma unroll 4
      for (int d = 0; d < cD; d += 2) {
        float2 fiv = *(const float2*)(fi + d);
        float2 fbv = *(const float2*)(fbp + d);
        float2 xv  = *(const float2*)(xr + d);
        float f0 = fract1(fmaf(xv.x, fiv.x, fbv.x) + srev);
        float f1 = fract1(fmaf(xv.y, fiv.y, fbv.y) + srev);
        uc += cos_rev(f0);
        us += sin_rev(f0);
        uc += cos_rev(f1);
        us += sin_rev(f1);
      }
      U[T * cN + ns * 32 + nl]  = uc;
      Vv[T * cN + ns * 32 + nl] = us;
    }
  }
}

// ---------------- res projection + attn-out + combine (per layer) ------------
// grid 512 (1 token/block) x 256 thr; thread: d4=t&31 (4-col group), nh=t>>5 (8 n-chunks)
__global__ __launch_bounds__(256) void k_res(const float* __restrict__ U, const float* __restrict__ Vv,
                                             const float* __restrict__ pTR, const float* __restrict__ pTI,
                                             const float* __restrict__ ctx, const float* __restrict__ x,
                                             const float* __restrict__ w_out, const float* __restrict__ b_out,
                                             const float* __restrict__ out_scale,
                                             const float* __restrict__ attn_scale, const float* __restrict__ res_scale,
                                             int l, float* __restrict__ xout, unsigned short* __restrict__ xbf) {
  int T = blockIdx.x;
  int t = threadIdx.x;
  __shared__ __align__(16) float uvU[512], uvV[512];
  __shared__ __align__(16) float4 part[8][32];
  uvU[t]       = U[T * cN + t];
  uvU[t + 256] = U[T * cN + 256 + t];
  uvV[t]       = Vv[T * cN + t];
  uvV[t + 256] = Vv[T * cN + 256 + t];
  __syncthreads();
  int d4 = t & 31, nh = t >> 5;
  float a0 = 0.f, a1 = 0.f, a2 = 0.f, a3 = 0.f;
  const float* prB = pTR + (size_t)(l * cN) * cD + d4 * 4;
  const float* piB = pTI + (size_t)(l * cN) * cD + d4 * 4;
  int n0 = nh * 64;
#pragma unroll 4
  for (int n = n0; n < n0 + 64; ++n) {
    float4 pr = *(const float4*)(prB + n * cD);
    float4 pi = *(const float4*)(piB + n * cD);
    float wr = uvU[n], wi = uvV[n];
    a0 = fmaf(wr, pr.x, fmaf(wi, pi.x, a0));
    a1 = fmaf(wr, pr.y, fmaf(wi, pi.y, a1));
    a2 = fmaf(wr, pr.z, fmaf(wi, pi.z, a2));
    a3 = fmaf(wr, pr.w, fmaf(wi, pi.w, a3));
  }
  if (nh > 0) part[nh][d4] = make_float4(a0, a1, a2, a3);
  __syncthreads();
  if (nh == 0) {
    float rr[4] = { a0, a1, a2, a3 };
#pragma unroll
    for (int j = 1; j < 8; ++j) {
      float4 p = part[j][d4];
      rr[0] += p.x; rr[1] += p.y; rr[2] += p.z; rr[3] += p.w;
    }
    int s = T & 255;
    int di = d4 * 4;
    float4 cx  = *(const float4*)(ctx + T * cD + di);
    float4 wo  = *(const float4*)(w_out + l * cD + di);
    float4 bo  = *(const float4*)(b_out + l * cD + di);
    float4 osc = *(const float4*)(out_scale + l * cD + di);
    float4 xv  = *(const float4*)(x + T * cD + di);
    float as = attn_scale[l], rs = res_scale[l];
    float sphi = (float)s * PHI_F;
    float cxa[4] = { cx.x, cx.y, cx.z, cx.w };
    float woa[4] = { wo.x, wo.y, wo.z, wo.w };
    float boa[4] = { bo.x, bo.y, bo.z, bo.w };
    float osa[4] = { osc.x, osc.y, osc.z, osc.w };
    float xva[4] = { xv.x, xv.y, xv.z, xv.w };
    float oa[4];
#pragma unroll
    for (int c = 0; c < 4; ++c) {
      float th = fmaf(cxa[c], 1.f / (1.f + fabsf(woa[c])), boa[c]) + sphi;
      float f = fract1(th * INV2PI_F);
      float ao = osa[c] * (cos_rev(f) + sin_rev(f));
      float r = rr[c];
      float sil = r / (1.f + __expf(-r));
      oa[c] = fmaf(as, ao, fmaf(rs, sil, xva[c]));
    }
    *(float4*)(xout + T * cD + di) = make_float4(oa[0], oa[1], oa[2], oa[3]);
    if (xbf) {
      ushort4 b4 = { f2bf(oa[0]), f2bf(oa[1]), f2bf(oa[2]), f2bf(oa[3]) };
      *(ushort4*)(xbf + T * cD + di) = b4;
    }
  }
}

// ---------------- final logits GEMM: barrier-free streaming MFMA -------------
// grid 1572 = 786 v-chunks x 2 m-halves (paired); 512 thr = 8 waves.
// wave: 64 m x 32 v (fm=4, fv=2). A,B read directly as bf16 fragments (L2-hot).
__global__ __launch_bounds__(512, 4) void k_gemm(const unsigned short* __restrict__ Xbf,
                                                 const unsigned short* __restrict__ Wbf,
                                                 float* __restrict__ out) {
  __shared__ __align__(16) float Cw[8][16 * 36];    // 18KB: per-wave C transpose staging
  int t = threadIdx.x, bid = blockIdx.x;
  int v0 = (bid >> 1) * 64, m0 = (bid & 1) * 256;
  int wid = t >> 6, lane = t & 63, lr = lane & 15, lk = lane >> 4;
  int wm = (wid >> 1) * 64, wv = (wid & 1) * 32;
  const bf16x8* Xp = (const bf16x8*)Xbf;            // frag idx = row*16 + ks*4 + lk
  const bf16x8* Wp = (const bf16x8*)Wbf;
  bf16x8 b[4][2];
#pragma unroll
  for (int ks = 0; ks < 4; ++ks)
#pragma unroll
    for (int fv = 0; fv < 2; ++fv)
      b[ks][fv] = Wp[(size_t)(v0 + wv + fv * 16 + lr) * 16 + ks * 4 + lk];
  bf16x8 aCur[4], aNxt[4];
#pragma unroll
  for (int fm = 0; fm < 4; ++fm)
    aCur[fm] = Xp[(m0 + wm + fm * 16 + lr) * 16 + lk];
  f32x4 acc[4][2];
#pragma unroll
  for (int fm = 0; fm < 4; ++fm)
#pragma unroll
    for (int fv = 0; fv < 2; ++fv) acc[fm][fv] = (f32x4){0.f, 0.f, 0.f, 0.f};
#pragma unroll
  for (int ks = 0; ks < 4; ++ks) {
    if (ks < 3) {
#pragma unroll
      for (int fm = 0; fm < 4; ++fm)
        aNxt[fm] = Xp[(m0 + wm + fm * 16 + lr) * 16 + (ks + 1) * 4 + lk];
    }
#pragma unroll
    for (int fm = 0; fm < 4; ++fm)
#pragma unroll
      for (int fv = 0; fv < 2; ++fv)
        acc[fm][fv] = __builtin_amdgcn_mfma_f32_16x16x32_bf16(aCur[fm], b[ks][fv], acc[fm][fv], 0, 0, 0);
#pragma unroll
    for (int fm = 0; fm < 4; ++fm) aCur[fm] = aNxt[fm];
  }
  // epilogue: per-wave LDS transpose -> two float4 stores per fm (64B segments)
  float* Cp = &Cw[wid][0];
  int rowl = lane >> 2, cg = lane & 3;
#pragma unroll
  for (int fm = 0; fm < 4; ++fm) {
#pragma unroll
    for (int fv = 0; fv < 2; ++fv)
#pragma unroll
      for (int r = 0; r < 4; ++r)
        Cp[(lk * 4 + r) * 36 + fv * 16 + lr] = acc[fm][fv][r];
    float4 c0 = *(const float4*)&Cp[rowl * 36 + cg * 4];
    float4 c1 = *(const float4*)&Cp[rowl * 36 + 16 + cg * 4];
    size_t rb = (size_t)(m0 + wm + fm * 16 + rowl) * cV;
    int cb0 = v0 + wv + cg * 4;
    int cb1 = cb0 + 16;
    if (cb1 + 3 < cV) {
      *(float4*)(out + rb + cb0) = c0;
      *(float4*)(out + rb + cb1) = c1;
    } else {
      float ca0[4] = { c0.x, c0.y, c0.z, c0.w };
      float ca1[4] = { c1.x, c1.y, c1.z, c1.w };
#pragma unroll
      for (int j = 0; j < 4; ++j) {
        if (cb0 + j < cV) out[rb + cb0 + j] = ca0[j];
        if (cb1 + j < cV) out[rb + cb1 + j] = ca1[j];
      }
    }
  }
}

extern "C" void kernel_launch(void* const* d_in, const int* in_sizes, int n_in,
                              void* d_out, int out_size, void* d_ws, size_t ws_size,
                              hipStream_t stream) {
  const int*   tokens    = (const int*)d_in[0];
  const float* emb       = (const float*)d_in[1];
  const float* wq        = (const float*)d_in[2];
  const float* bq        = (const float*)d_in[3];
  const float* wk        = (const float*)d_in[4];
  const float* bk        = (const float*)d_in[5];
  const float* w_out     = (const float*)d_in[6];
  const float* b_out     = (const float*)d_in[7];
  const float* out_scale = (const float*)d_in[8];
  const float* Wf        = (const float*)d_in[9];
  const float* Bf        = (const float*)d_in[10];
  const float* pr        = (const float*)d_in[11];
  const float* pi        = (const float*)d_in[12];
  const float* attn_s    = (const float*)d_in[13];
  const float* res_s     = (const float*)d_in[14];
  const float* out_proj  = (const float*)d_in[15];
  float* out = (float*)d_out;
  float* ws  = (float*)d_ws;

  float*  states = ws;                     // 65536
  float*  x1     = ws + 65536;             // 65536
  float*  x2     = ws + 131072;            // 65536
  float*  ctx    = ws + 196608;            // 65536
  float2* mc     = (float2*)(ws + 262144); // 131072 floats
  float*  U      = ws + 393216;            // 262144
  float*  Vv     = ws + 655360;            // 262144
  float*  pTR    = ws + 917504;            // 131072
  float*  pTI    = ws + 1048576;           // 131072
  unsigned short* X2bf = (unsigned short*)(ws + 1179648); // 65536 ushorts
  unsigned short* Wbf  = (unsigned short*)(ws + 1212416); // 50304*128 ushorts (12.9MB)

  k_setup<<<768 + (cVp * 16) / 256, 256, 0, stream>>>(tokens, emb, mc, pr, pi, pTR, pTI,
                                                      out_proj, Wbf);
  k_scan<<<1, 256, 0, stream>>>(mc, states);

  const float* xin = states;
  float* xouts[2] = { x1, x2 };
  for (int l = 0; l < 2; ++l) {
    k_layer<<<512, 512, 0, stream>>>(xin, states, wq + l * 128, bq + l * 128,
                                     wk + l * 128, bk + l * 128,
                                     Wf + l * 65536, Bf + l * 65536, ctx, U, Vv);
    k_res<<<512, 256, 0, stream>>>(U, Vv, pTR, pTI, ctx, xin, w_out, b_out, out_scale,
                                   attn_s, res_s, l, xouts[l],
                                   (l == 1) ? X2bf : (unsigned short*)nullptr);
    xin = xouts[l];
  }
  k_gemm<<<1572, 512, 0, stream>>>(X2bf, Wbf, out);
}